// Round 8
// baseline (261.316 us; speedup 1.0000x reference)
//
#include <hip/hip_runtime.h>
#include <hip/hip_bf16.h>

// LSS voxel pooling: B=2,N=6,D=48,FH=16,FW=44,C=80 -> out [2,80,1,256,256]
// R5: coalesced-atomic flush into voxel-major S (scatter 133 -> ~63us).
// R6/R7 crash ROOT CAUSE: phase 1 used `if (tid < 352)` with a 256-thread
// block -> s_base[256..351] never written -> garbage voxel ids -> OOB flush
// address -> page fault. R8 = R7 with phase 1 as a 2-trip coverage LOOP.
// Phase 2 is h-outer with fully-coalesced row reads (880 contiguous float4
// per (bn,d,h) row), register accumulators per (w,c4), voxel-major flush.
//
// Numerics (verified R1-R5, absmax 0.016): f64 geometry seeded with bit-exact
// f32 frustum values + f32-valued bounds constants; trunc-toward-zero.

#define NCH       80
#define GRID_HW   65536    // 256*256
#define OUT_PER_B 5242880  // 80*65536
#define HSTRIDE   3520     // 44*80 floats between h rows
#define PTS_PER_BN 33792   // 48*16*44
#define S_FLOATS  10485760 // 2*65536*80
#define S_BYTES   41943040

__device__ inline void inv3(const double a[9], double inv[9]) {
    double c00 =  a[4]*a[8] - a[5]*a[7];
    double c01 = -(a[3]*a[8] - a[5]*a[6]);
    double c02 =  a[3]*a[7] - a[4]*a[6];
    double det = a[0]*c00 + a[1]*c01 + a[2]*c02;
    double id  = 1.0/det;
    inv[0] = c00*id;
    inv[1] = (a[2]*a[7]-a[1]*a[8])*id;
    inv[2] = (a[1]*a[5]-a[2]*a[4])*id;
    inv[3] = c01*id;
    inv[4] = (a[0]*a[8]-a[2]*a[6])*id;
    inv[5] = (a[2]*a[3]-a[0]*a[5])*id;
    inv[6] = c02*id;
    inv[7] = (a[1]*a[6]-a[0]*a[7])*id;
    inv[8] = (a[0]*a[4]-a[1]*a[3])*id;
}

// tw[bn*24 + 0..8]=inv(post_rots), [9..17]=rots@inv(intrins),
// [18..20]=post_trans, [21..23]=trans (double)
__global__ void prep_kernel(const float* __restrict__ rots,
                            const float* __restrict__ trans,
                            const float* __restrict__ intrins,
                            const float* __restrict__ post_rots,
                            const float* __restrict__ post_trans,
                            double* __restrict__ tw) {
    int bn = threadIdx.x;
    if (bn >= 12) return;
    double pr[9], kk[9], rt[9], ipr[9], ik[9];
    #pragma unroll
    for (int i = 0; i < 9; i++) {
        pr[i] = (double)post_rots[bn*9 + i];
        kk[i] = (double)intrins[bn*9 + i];
        rt[i] = (double)rots[bn*9 + i];
    }
    inv3(pr, ipr);
    inv3(kk, ik);
    double* o = tw + bn*24;
    #pragma unroll
    for (int i = 0; i < 9; i++) o[i] = ipr[i];
    #pragma unroll
    for (int r = 0; r < 3; r++)
        #pragma unroll
        for (int c = 0; c < 3; c++)
            o[9 + r*3 + c] = rt[r*3+0]*ik[0*3+c] + rt[r*3+1]*ik[1*3+c] + rt[r*3+2]*ik[2*3+c];
    #pragma unroll
    for (int i = 0; i < 3; i++) o[18 + i] = (double)post_trans[bn*3 + i];
    #pragma unroll
    for (int i = 0; i < 3; i++) o[21 + i] = (double)trans[bn*3 + i];
}

__global__ __launch_bounds__(256) void zero_kernel(float4* __restrict__ p, int n4) {
    int i = blockIdx.x * 256 + threadIdx.x;
    int stride = gridDim.x * 256;
    for (; i < n4; i += stride) p[i] = make_float4(0.f, 0.f, 0.f, 0.f);
}

// Voxel id for point (bn,d,h,w): (b<<16)|(gy<<8)|gx, or -1 if clipped.
__device__ inline int voxel_of(const double* t, int b, int d, int h, int w) {
    float xsv = (w == 43) ? 703.0f : (float)((double)w * (703.0 / 43.0));
    float ysv = (float)(h * 17);
    float dsv = __fadd_rn(2.0f, __fmul_rn((float)(56.0 / 48.0), (float)d));

    double px = (double)xsv - t[18];
    double py = (double)ysv - t[19];
    double pz = (double)dsv - t[20];
    double q0 = t[0]*px + t[1]*py + t[2]*pz;
    double q1 = t[3]*px + t[4]*py + t[5]*pz;
    double q2 = t[6]*px + t[7]*py + t[8]*pz;
    q0 *= q2;
    q1 *= q2;
    double e0 = t[9]*q0  + t[10]*q1 + t[11]*q2 + t[21];
    double e1 = t[12]*q0 + t[13]*q1 + t[14]*q2 + t[22];
    double e2 = t[15]*q0 + t[16]*q1 + t[17]*q2 + t[23];

    const double lxy = (double)(-51.2f);
    const double dxy = (double)(0.4f);
    int gx = (int)((e0 - lxy) / dxy);
    int gy = (int)((e1 - lxy) / dxy);
    int gz = (int)((e2 - (double)(-10.0f)) / (double)(20.0f));
    if (gx >= 0 && gx < 256 && gy >= 0 && gy < 256 && gz == 0)
        return (b << 16) | (gy << 8) | gx;
    return -1;
}

// Block = 8-h half of one (bn,d) slice. Grid = 12*48*2 = 1152.
__global__ __launch_bounds__(256) void scatter_grid_kernel(const float* __restrict__ x,
                                                           const double* __restrict__ ws,
                                                           float* __restrict__ S) {
    __shared__ int      s_base[8 * 44];   // per (hl,w) voxel id or -1
    __shared__ int      s_colbase[44];    // representative voxel (>=0; 0 if none)
    __shared__ unsigned s_mask[44];       // hl-bits matching colbase
    __shared__ unsigned s_fb[44];         // hl-bits with differing voxel (fallback)

    const int tid   = threadIdx.x;
    const int bid   = blockIdx.x;
    const int bn    = bid / 96;
    const int rem   = bid - bn * 96;
    const int d     = rem >> 1;
    const int h0    = (rem & 1) * 8;
    const int b     = bn / 6;
    const double* t = ws + bn * 24;

    // ---- phase 1: per-point geometry; LOOP so all 352 entries get written ----
    for (int idx = tid; idx < 352; idx += 256) {
        const int hl = idx / 44;
        const int w  = idx - hl * 44;
        s_base[idx] = voxel_of(t, b, d, h0 + hl, w);
    }
    __syncthreads();

    // ---- phase 1b: per-column representative + masks ----
    if (tid < 44) {
        int cb = -1; unsigned mm = 0, fb = 0;
        #pragma unroll
        for (int hl = 0; hl < 8; hl++) {
            int pb = s_base[hl * 44 + tid];
            if (pb >= 0) {
                if (cb < 0) cb = pb;
                if (pb == cb) mm |= (1u << hl);
                else          fb |= (1u << hl);
            }
        }
        s_colbase[tid] = (cb >= 0) ? cb : 0;   // always a safe index
        s_mask[tid]    = mm;                   // mm==0 when cb was -1
        s_fb[tid]      = fb;
    }
    __syncthreads();

    // ---- phase 2: 880 float4 items; k=0..2 always valid, k=3 iff tid<112 ----
    unsigned mmk[4], fbk[4];
    int wk[4], c4k[4], cbk[4];
    #pragma unroll
    for (int k = 0; k < 4; k++) {
        const bool val = (k < 3) || (tid < 112);
        const int  j   = val ? (k * 256 + tid) : tid;   // in-range either way
        const int  w   = j / 20;                        // <= 43
        wk[k]  = w;
        c4k[k] = j - w * 20;
        mmk[k] = val ? s_mask[w] : 0u;
        fbk[k] = val ? s_fb[w]   : 0u;
        cbk[k] = s_colbase[w];                          // >= 0 always
    }

    float4 acc[4];
    #pragma unroll
    for (int k = 0; k < 4; k++) acc[k] = make_float4(0.f, 0.f, 0.f, 0.f);

    const float* xb0 = x + ((size_t)bn * PTS_PER_BN + (size_t)d * 704 + (size_t)h0 * 44) * NCH;
    for (int hl = 0; hl < 8; hl++) {
        const float4* row = (const float4*)(xb0 + (size_t)hl * HSTRIDE);
        #pragma unroll
        for (int k = 0; k < 4; k++) {
            const int j = wk[k] * 20 + c4k[k];          // < 880
            if ((mmk[k] >> hl) & 1u) {
                float4 v = row[j];                      // coalesced: lanes consecutive
                acc[k].x += v.x; acc[k].y += v.y; acc[k].z += v.z; acc[k].w += v.w;
            } else if ((fbk[k] >> hl) & 1u) {           // general-input path (unused here)
                float4 v = row[j];
                int vb = s_base[hl * 44 + wk[k]];       // >= 0 when fb bit set
                float* sp = S + (size_t)vb * NCH + c4k[k] * 4;
                atomicAdd(sp + 0, v.x);
                atomicAdd(sp + 1, v.y);
                atomicAdd(sp + 2, v.z);
                atomicAdd(sp + 3, v.w);
            }
        }
    }

    // ---- flush: coalesced atomics into voxel-major S ----
    #pragma unroll
    for (int k = 0; k < 4; k++) {
        if (mmk[k]) {
            float* sp = S + (size_t)cbk[k] * NCH + c4k[k] * 4;
            atomicAdd(sp + 0, acc[k].x);
            atomicAdd(sp + 1, acc[k].y);
            atomicAdd(sp + 2, acc[k].z);
            atomicAdd(sp + 3, acc[k].w);
        }
    }
}

// S[b*65536+v][c] -> out[b][c][v]; coalesced both sides; writes ALL of out.
__global__ __launch_bounds__(256) void transpose_kernel(const float* __restrict__ S,
                                                        float* __restrict__ out) {
    __shared__ float tile[64 * 81];
    const int tid = threadIdx.x;
    const int b   = blockIdx.x >> 10;
    const int v0  = (blockIdx.x & 1023) * 64;
    const float* src = S + ((size_t)(b << 16) + v0) * NCH;
    #pragma unroll
    for (int i = 0; i < 20; i++) {
        int j = i * 256 + tid;          // coalesced read
        int v = j / 80;
        int c = j - v * 80;
        tile[v * 81 + c] = src[j];
    }
    __syncthreads();
    float* dst = out + (size_t)b * OUT_PER_B + v0;
    #pragma unroll
    for (int i = 0; i < 20; i++) {
        int k  = i * 256 + tid;
        int c  = k >> 6;
        int lv = k & 63;
        dst[(size_t)c * GRID_HW + lv] = tile[lv * 81 + c];
    }
}

// Fallback (ws too small): direct atomics into out; R3/R5 structure.
__global__ __launch_bounds__(256) void scatter_direct_kernel(const float* __restrict__ x,
                                                             const double* __restrict__ ws,
                                                             float* __restrict__ out) {
    __shared__ int      s_base[704];
    __shared__ int      s_colbase[44];
    __shared__ unsigned s_mask[44];
    __shared__ unsigned s_fb[44];

    const int tid = threadIdx.x;
    const int bn  = blockIdx.x / 48;
    const int d   = blockIdx.x - bn * 48;
    const int b   = bn / 6;
    const double* t = ws + bn * 24;

    for (int idx = tid; idx < 704; idx += 256) {
        const int h = idx / 44;
        const int w = idx - h * 44;
        s_base[idx] = voxel_of(t, b, d, h, w);
    }
    __syncthreads();
    if (tid < 44) {
        int cb = -1; unsigned mm = 0, fb = 0;
        #pragma unroll
        for (int h = 0; h < 16; h++) {
            int pb = s_base[h * 44 + tid];
            if (pb >= 0) {
                if (cb < 0) cb = pb;
                if (pb == cb) mm |= (1u << h);
                else          fb |= (1u << h);
            }
        }
        s_colbase[tid] = (cb >= 0) ? cb : 0;
        s_mask[tid]    = mm;
        s_fb[tid]      = fb;
    }
    __syncthreads();

    const float* xb0 = x + ((size_t)bn * PTS_PER_BN + (size_t)d * 704) * NCH;
    for (int pass = 0; pass < 4; pass++) {
        int item = pass * 256 + tid;
        if (item >= 880) break;
        int w  = item / 20;
        int c4 = item - w * 20;
        unsigned mm = s_mask[w];
        unsigned fb = s_fb[w];
        if (!(mm | fb)) continue;
        const float* xb = xb0 + (size_t)w * NCH + c4 * 4;
        float ax = 0.f, ay = 0.f, az = 0.f, aw = 0.f;
        for (int h = 0; h < 16; h++) {
            if ((mm >> h) & 1u) {
                float4 v = *(const float4*)(xb + h * HSTRIDE);
                ax += v.x; ay += v.y; az += v.z; aw += v.w;
            } else if ((fb >> h) & 1u) {
                float4 v = *(const float4*)(xb + h * HSTRIDE);
                int vb = s_base[h * 44 + w];
                float* o = out + (size_t)(vb >> 16) * OUT_PER_B + (vb & 65535);
                atomicAdd(o + (size_t)(c4*4 + 0) * GRID_HW, v.x);
                atomicAdd(o + (size_t)(c4*4 + 1) * GRID_HW, v.y);
                atomicAdd(o + (size_t)(c4*4 + 2) * GRID_HW, v.z);
                atomicAdd(o + (size_t)(c4*4 + 3) * GRID_HW, v.w);
            }
        }
        if (mm) {
            int vb = s_colbase[w];
            float* o = out + (size_t)(vb >> 16) * OUT_PER_B + (vb & 65535);
            atomicAdd(o + (size_t)(c4*4 + 0) * GRID_HW, ax);
            atomicAdd(o + (size_t)(c4*4 + 1) * GRID_HW, ay);
            atomicAdd(o + (size_t)(c4*4 + 2) * GRID_HW, az);
            atomicAdd(o + (size_t)(c4*4 + 3) * GRID_HW, aw);
        }
    }
}

extern "C" void kernel_launch(void* const* d_in, const int* in_sizes, int n_in,
                              void* d_out, int out_size, void* d_ws, size_t ws_size,
                              hipStream_t stream) {
    const float* x          = (const float*)d_in[0];
    const float* rots       = (const float*)d_in[1];
    const float* trans      = (const float*)d_in[2];
    const float* intrins    = (const float*)d_in[3];
    const float* post_rots  = (const float*)d_in[4];
    const float* post_trans = (const float*)d_in[5];
    float* out = (float*)d_out;

    if (ws_size >= (size_t)S_BYTES + 4096) {
        float*  S  = (float*)d_ws;
        double* tw = (double*)((char*)d_ws + S_BYTES);
        zero_kernel<<<2560, 256, 0, stream>>>((float4*)S, S_FLOATS / 4);
        prep_kernel<<<1, 64, 0, stream>>>(rots, trans, intrins, post_rots, post_trans, tw);
        scatter_grid_kernel<<<1152, 256, 0, stream>>>(x, tw, S);
        transpose_kernel<<<2048, 256, 0, stream>>>(S, out);
    } else {
        double* tw = (double*)d_ws;
        zero_kernel<<<2560, 256, 0, stream>>>((float4*)out, out_size / 4);
        prep_kernel<<<1, 64, 0, stream>>>(rots, trans, intrins, post_rots, post_trans, tw);
        scatter_direct_kernel<<<576, 256, 0, stream>>>(x, tw, out);
    }
}